// Round 4
// baseline (221.356 us; speedup 1.0000x reference)
//
#include <hip/hip_runtime.h>
#include <hip/hip_bf16.h>

typedef unsigned short u16;
typedef __bf16 bf16x8 __attribute__((ext_vector_type(8)));
typedef float f32x4 __attribute__((ext_vector_type(4)));
typedef unsigned short u16x8 __attribute__((ext_vector_type(8)));
typedef unsigned short u16x4 __attribute__((ext_vector_type(4)));

__device__ __forceinline__ float bf2f(u16 u) {
  unsigned x = ((unsigned)u) << 16;
  return __builtin_bit_cast(float, x);
}
__device__ __forceinline__ u16 f2bf(float f) {
  unsigned u = __builtin_bit_cast(unsigned, f);
  u += 0x7fffu + ((u >> 16) & 1u);
  return (u16)(u >> 16);
}

// async global -> LDS, 16B per lane; lds base wave-uniform, HW scatters base+lane*16.
__device__ __forceinline__ void gload16(const u16* g, u16* lds) {
  __builtin_amdgcn_global_load_lds(
      (const __attribute__((address_space(1))) void*)g,
      (__attribute__((address_space(3))) void*)lds,
      16, 0, 0);
}

__device__ __forceinline__ void bar() {
  __builtin_amdgcn_sched_barrier(0);
  __builtin_amdgcn_s_barrier();
  __builtin_amdgcn_sched_barrier(0);
}
template <int N> __device__ __forceinline__ void wait_vm() {
  asm volatile("s_waitcnt vmcnt(%0)" :: "n"(N) : "memory");
  __builtin_amdgcn_sched_barrier(0);
}
__device__ __forceinline__ void wait_lgkm0() {
  asm volatile("s_waitcnt lgkmcnt(0)" ::: "memory");
  __builtin_amdgcn_sched_barrier(0);
}

// =========================================================================
// 128x256 bf16 GEMM, BK=32, 3-deep LDS ring, ONE barrier per K-tile (R4).
// Rationale (R3 post-mortem): at 256² tiles / 128KB LDS the block is alone
// on its CU and all 8 waves are barrier-lockstepped, so the per-phase LDS
// fragment-read drain (~400-800cy/CU) serializes with MFMA (~310cy) ->
// MfmaUtil pinned at ~26% regardless of phase width (R1==R3).  Fix:
// 72KB LDS + VGPR<=128 -> 2 blocks/CU (cross-block overlap, the m97
// mechanism) + minimal sync: per K-tile {vmcnt(3); bar; 8 ds_read_b128;
// 3 gload16 -> buf (s+2)%3; lgkm0; 16 MFMA}.
// Race-freedom of the single-barrier ring: phase s stages into buf
// (s+2)%3 == (s-1)%3, whose last readers (phase s-1) completed their
// ds_reads before their own lgkm0+MFMA, hence before bar(s); barrier-
// per-phase limits wave skew to one segment.  vmcnt(3) at phase s retires
// exactly tile s's 3 loads (issued phase s-2; tile s+1's 3 remain).
// Final phase drains (vmcnt 0).  Prologue stages tiles 0,1 (6 loads).
// C[M,N] = A[M,K] * B[N,K]^T * cscale.  OUT_MODE: 1 = bf16, 0 = f32.
// 512 thr = 8 waves (2M x 4N), per-wave 64x64 = 4x4 fragments 16x16x32.
// LDS (u16): A bufs p*4096 (p=0..2), B bufs 12288 + p*8192; total 36864
// u16 = 72KB.  Layout [rows][32k] row-major, chunk swizzle: elem (r,c)
// chunk cc stored at cc ^ h4(r), h4 = ((r>>1)^(r>>3))&3 -> per dword-pass
// 2 lanes/bank (free, m136).  gload dest linear; source pre-swizzled.
// =========================================================================
__device__ __forceinline__ int h4(int r) { return ((r >> 1) ^ (r >> 3)) & 3; }

#define ABUF(p) ((p) * 4096)
#define BBUF(p) (12288 + (p) * 8192)

struct GS {
  const u16 *gA, *gB0, *gB1;   // per-lane staging src (k=0)
  int dst0, dst1;              // LDS elem offsets within a buf
  int aoff[4], boff[4];        // frag LDS elem offsets within a buf
  u16* lds;
};

template <bool STG, int W>
__device__ __forceinline__ void phase128(const GS& g, int s, int p, f32x4 (&acc)[4][4]) {
  wait_vm<W>();                         // my slice of tile s has landed
  bar();                                // publish all waves' slices
  bf16x8 a[4], b[4];
#pragma unroll
  for (int i = 0; i < 4; ++i) a[i] = *(const bf16x8*)(g.lds + ABUF(p) + g.aoff[i]);
#pragma unroll
  for (int j = 0; j < 4; ++j) b[j] = *(const bf16x8*)(g.lds + BBUF(p) + g.boff[j]);
  if (STG) {
    const int kt = (s + 2) * 32;
    const int p2 = (p + 2) % 3;         // == (s+2)%3, buf freed last phase
    gload16(g.gA + kt, g.lds + ABUF(p2) + g.dst0);
    gload16(g.gB0 + kt, g.lds + BBUF(p2) + g.dst0);
    gload16(g.gB1 + kt, g.lds + BBUF(p2) + g.dst1);
  }
  wait_lgkm0();
  __builtin_amdgcn_s_setprio(1);
#pragma unroll
  for (int i = 0; i < 4; ++i)
#pragma unroll
    for (int j = 0; j < 4; ++j)
      acc[i][j] = __builtin_amdgcn_mfma_f32_16x16x32_bf16(a[i], b[j], acc[i][j], 0, 0, 0);
  __builtin_amdgcn_s_setprio(0);
}

template <int OUT_MODE, int NX, int NT>
__device__ __forceinline__ void gemm128x256(
    const u16* __restrict__ A, int lda, const u16* __restrict__ B, int ldb,
    void* __restrict__ C, int ldc, float cscale, u16* lds, int bid)
{
  static_assert(NT % 3 == 2 && NT >= 5, "phase schedule needs NT==2 mod 3");
  const int by = (bid & 7) + 8 * (bid / (8 * NX));
  const int bx = (bid >> 3) % NX;
  const int m0 = by * 128, n0 = bx * 256;
  const int t = threadIdx.x;
  const int w = t >> 6, l = t & 63;
  const int wm = (w >> 2) * 64, wn = (w & 3) * 64;
  const int fr = l & 15, q = l >> 4;

  GS g;
  g.lds = lds;
  {
    const int sA = w * 64 + l;               // 0..511
    const int rA = sA >> 2, cA = sA & 3;     // A rows 0..127 / B rows 0..127
    const int sB1 = 512 + sA;
    const int rB1 = sB1 >> 2, cB1 = sB1 & 3; // B rows 128..255
    g.gA  = A + (size_t)(m0 + rA) * lda + (cA ^ h4(rA)) * 8;
    g.gB0 = B + (size_t)(n0 + rA) * ldb + (cA ^ h4(rA)) * 8;
    g.gB1 = B + (size_t)(n0 + rB1) * ldb + (cB1 ^ h4(rB1)) * 8;
    g.dst0 = sA * 8;
    g.dst1 = sB1 * 8;
  }
#pragma unroll
  for (int i = 0; i < 4; ++i) {
    const int ra = wm + 16 * i + fr;
    const int rb = wn + 16 * i + fr;
    g.aoff[i] = ra * 32 + (q ^ h4(ra)) * 8;
    g.boff[i] = rb * 32 + (q ^ h4(rb)) * 8;
  }

  f32x4 acc[4][4] = {};

  // prologue: tiles 0 and 1 (3 loads each)
  gload16(g.gA + 0,  lds + ABUF(0) + g.dst0);
  gload16(g.gB0 + 0, lds + BBUF(0) + g.dst0);
  gload16(g.gB1 + 0, lds + BBUF(0) + g.dst1);
  gload16(g.gA + 32,  lds + ABUF(1) + g.dst0);
  gload16(g.gB0 + 32, lds + BBUF(1) + g.dst0);
  gload16(g.gB1 + 32, lds + BBUF(1) + g.dst1);

  for (int s = 0; s < NT - 2; s += 3) {      // s = 0..NT-3, all staged
    phase128<true, 3>(g, s, 0, acc);
    phase128<true, 3>(g, s + 1, 1, acc);
    phase128<true, 3>(g, s + 2, 2, acc);
  }
  phase128<false, 3>(g, NT - 2, (NT - 2) % 3, acc);
  phase128<false, 0>(g, NT - 1, (NT - 1) % 3, acc);

  // ---- epilogue: per-wave LDS round-trip, coalesced 16B stores ----
  // C/D layout (m89): col = lane&15, row = (lane>>4)*4 + reg
  bar();                                     // all LDS bufs now dead
  const int er = q * 4, ec = fr;
  const int rg = l >> 3, c = l & 7;

  if (OUT_MODE == 1) {
    u16* Ch = (u16*)C;
    u16* eb = lds + w * 4608;                // 64 rows x 72 u16 per wave
#pragma unroll
    for (int i = 0; i < 4; ++i)
#pragma unroll
      for (int j = 0; j < 4; ++j)
#pragma unroll
        for (int r = 0; r < 4; ++r)
          eb[(16 * i + er + r) * 72 + 16 * j + ec] = f2bf(acc[i][j][r] * cscale);
#pragma unroll
    for (int k = 0; k < 8; ++k) {
      const int row = k * 8 + rg;
      u16x8 v = *(const u16x8*)(eb + row * 72 + c * 8);
      *(u16x8*)(Ch + (size_t)(m0 + wm + row) * ldc + n0 + wn + c * 8) = v;
    }
  } else {
    float* Cf = (float*)C;
    float* eb = (float*)lds + w * 2304;      // 32 rows x 72 f32 per wave
#pragma unroll
    for (int half = 0; half < 2; ++half) {
#pragma unroll
      for (int ii = 0; ii < 2; ++ii)
#pragma unroll
        for (int j = 0; j < 4; ++j)
#pragma unroll
          for (int r = 0; r < 4; ++r)
            eb[(16 * ii + er + r) * 72 + 16 * j + ec] = acc[2 * half + ii][j][r] * cscale;
#pragma unroll
      for (int k = 0; k < 4; ++k) {
        const int row = k * 8 + rg;
        float4 v0 = *(const float4*)(eb + row * 72 + c * 4);
        float4 v1 = *(const float4*)(eb + row * 72 + (c + 8) * 4);
        float* dst = Cf + (size_t)(m0 + wm + 32 * half + row) * ldc + n0 + wn;
        *(float4*)(dst + c * 4) = v0;
        *(float4*)(dst + (c + 8) * 4) = v1;
      }
      if (half == 0) bar();                  // reuse eb for second half
    }
  }
}

// stage 1: QKV = E @ Wt^T  [4096 x 3072], K=1024.  grid 384 (32x12).
__global__ __launch_bounds__(512, 4) void gemm_qkv128(const u16* __restrict__ A,
                                                      const u16* __restrict__ B,
                                                      u16* __restrict__ C) {
  __shared__ __align__(16) u16 lds[36864];   // 72 KiB -> 2 blocks/CU
  gemm128x256<1, 12, 32>(A, 1024, B, 1024, C, 3072, 1.0f, lds, blockIdx.x);
}

// stage 2: S = (Q @ K^T)/32  [4096 x 4096], K=1024.  grid 512 (32x16).
__global__ __launch_bounds__(512, 4) void gemm_score128(const u16* __restrict__ QKV,
                                                        u16* __restrict__ S) {
  __shared__ __align__(16) u16 lds[36864];
  gemm128x256<1, 16, 32>(QKV, 3072, QKV + 1024, 3072, S, 4096, 0.03125f, lds, blockIdx.x);
}

// -------------------------------------------------------------------------
// stage 4: Out = P @ Vt^T  [4096 x 1024], K=4096 — split-K x4.
// 128 tiles (32x4) x 4 splits = 512 blocks = 2/CU; K=1024 per split.
// f32 partials (ws >= 146MB, confirmed running) or bf16 fallback.
// -------------------------------------------------------------------------
__global__ __launch_bounds__(512, 4) void gemm_pv128f(const u16* __restrict__ S,
                                                      const u16* __restrict__ Vt,
                                                      float* __restrict__ P4) {
  __shared__ __align__(16) u16 lds[36864];
  const int b = blockIdx.x;
  const int sp = b >> 7;                     // 0..3 K-split
  float* Cp = P4 + (size_t)sp * 4096 * 1024;
  gemm128x256<0, 4, 32>(S + sp * 1024, 4096, Vt + sp * 1024, 4096,
                        Cp, 1024, 1.0f, lds, b & 127);
}

__global__ __launch_bounds__(512, 4) void gemm_pv128h(const u16* __restrict__ S,
                                                      const u16* __restrict__ Vt,
                                                      u16* __restrict__ P4) {
  __shared__ __align__(16) u16 lds[36864];
  const int b = blockIdx.x;
  const int sp = b >> 7;
  u16* Cp = P4 + (size_t)sp * 4096 * 1024;
  gemm128x256<1, 4, 32>(S + sp * 1024, 4096, Vt + sp * 1024, 4096,
                        Cp, 1024, 1.0f, lds, b & 127);
}

// stage 5: Out = sum of 4 partials.  16B/thread out.
__global__ __launch_bounds__(256) void reduce4f(const float* __restrict__ P4,
                                                float* __restrict__ O) {
  const size_t i = ((size_t)blockIdx.x * 256 + threadIdx.x) * 4;
  const size_t st = (size_t)4096 * 1024;
  float4 a = *(const float4*)(P4 + i);
  float4 b = *(const float4*)(P4 + st + i);
  float4 c = *(const float4*)(P4 + 2 * st + i);
  float4 d = *(const float4*)(P4 + 3 * st + i);
  float4 o;
  o.x = (a.x + b.x) + (c.x + d.x);
  o.y = (a.y + b.y) + (c.y + d.y);
  o.z = (a.z + b.z) + (c.z + d.z);
  o.w = (a.w + b.w) + (c.w + d.w);
  *(float4*)(O + i) = o;
}

__global__ __launch_bounds__(256) void reduce4h(const u16* __restrict__ P4,
                                                float* __restrict__ O) {
  const size_t i = ((size_t)blockIdx.x * 256 + threadIdx.x) * 4;
  const size_t st = (size_t)4096 * 1024;
  u16x4 a = *(const u16x4*)(P4 + i);
  u16x4 b = *(const u16x4*)(P4 + st + i);
  u16x4 c = *(const u16x4*)(P4 + 2 * st + i);
  u16x4 d = *(const u16x4*)(P4 + 3 * st + i);
  float4 o;
  o.x = (bf2f(a.x) + bf2f(b.x)) + (bf2f(c.x) + bf2f(d.x));
  o.y = (bf2f(a.y) + bf2f(b.y)) + (bf2f(c.y) + bf2f(d.y));
  o.z = (bf2f(a.z) + bf2f(b.z)) + (bf2f(c.z) + bf2f(d.z));
  o.w = (bf2f(a.w) + bf2f(b.w)) + (bf2f(c.w) + bf2f(d.w));
  *(float4*)(O + i) = o;
}

// -------------------------------------------------------------------------
// stage 0 merged: blocks 0..4095 = E f32->bf16 cast; 4096..7167 = W transposes.
// -------------------------------------------------------------------------
__global__ __launch_bounds__(256) void prep(
    const float* __restrict__ E,
    const float* __restrict__ w0, const float* __restrict__ w1,
    const float* __restrict__ w2,
    u16* __restrict__ Ebf, u16* __restrict__ Wt)
{
  int b = blockIdx.x;
  if (b < 4096) {
    const int i = (b * 256 + threadIdx.x) * 4;
    float4 f = *(const float4*)(E + i);
    u16x4 o;
    o.x = f2bf(f.x); o.y = f2bf(f.y); o.z = f2bf(f.z); o.w = f2bf(f.w);
    *(u16x4*)(Ebf + i) = o;
  } else {
    b -= 4096;
    const int which = b >> 10;
    const int tile = b & 1023;
    const float* in = (which == 0) ? w0 : (which == 1) ? w1 : w2;
    u16* o = Wt + (size_t)which * 1024 * 1024;
    const int c0 = (tile & 31) * 32, r0 = (tile >> 5) * 32;
    __shared__ u16 tl[32][33];
    const int tx = threadIdx.x & 31, ty0 = threadIdx.x >> 5;
#pragma unroll
    for (int k = 0; k < 4; ++k) {
      const int ty = ty0 + k * 8;
      tl[ty][tx] = f2bf(in[(size_t)(r0 + ty) * 1024 + c0 + tx]);
    }
    __syncthreads();
#pragma unroll
    for (int k = 0; k < 4; ++k) {
      const int ty = ty0 + k * 8;
      o[(size_t)(c0 + ty) * 1024 + r0 + tx] = tl[tx][ty];
    }
  }
}

// -------------------------------------------------------------------------
// stage 3 merged: blocks 0..4095 = row softmax (in-place, bf16 S, scale
// pre-applied); blocks 4096..8191 = V transpose (32x32 tiles).
// -------------------------------------------------------------------------
__global__ __launch_bounds__(256) void softmax_tv(u16* __restrict__ S,
                                                  const u16* __restrict__ QKV,
                                                  u16* __restrict__ Vt) {
  __shared__ float red[8];
  __shared__ u16 tl[32][33];
  const int b = blockIdx.x;
  if (b < 4096) {
    const int N = 4096;
    u16* p = S + (size_t)b * N;
    const int t = threadIdx.x;
    u16x8 u0 = ((const u16x8*)p)[t * 2];
    u16x8 u1 = ((const u16x8*)p)[t * 2 + 1];
    float v[16];
#pragma unroll
    for (int i = 0; i < 8; ++i) v[i] = bf2f(u0[i]);
#pragma unroll
    for (int i = 0; i < 8; ++i) v[8 + i] = bf2f(u1[i]);

    float m = -1e30f;
#pragma unroll
    for (int i = 0; i < 16; ++i) m = fmaxf(m, v[i]);
#pragma unroll
    for (int off = 32; off; off >>= 1) m = fmaxf(m, __shfl_xor(m, off));
    if ((t & 63) == 0) red[t >> 6] = m;
    __syncthreads();
    m = fmaxf(fmaxf(red[0], red[1]), fmaxf(red[2], red[3]));

    float s = 0.f;
#pragma unroll
    for (int i = 0; i < 16; ++i) { v[i] = __expf(v[i] - m); s += v[i]; }
#pragma unroll
    for (int off = 32; off; off >>= 1) s += __shfl_xor(s, off);
    if ((t & 63) == 0) red[4 + (t >> 6)] = s;
    __syncthreads();
    s = (red[4] + red[5]) + (red[6] + red[7]);
    const float inv = 1.0f / s;

    u16x8 o0, o1;
#pragma unroll
    for (int i = 0; i < 8; ++i) o0[i] = f2bf(v[i] * inv);
#pragma unroll
    for (int i = 0; i < 8; ++i) o1[i] = f2bf(v[8 + i] * inv);
    ((u16x8*)p)[t * 2] = o0;
    ((u16x8*)p)[t * 2 + 1] = o1;
  } else {
    const int v = b - 4096;                       // 0..4095
    const int c0 = (v & 31) * 32;                 // V col 0..1023
    const int r0 = (v >> 5) * 32;                 // V row 0..4095
    const int tx = threadIdx.x & 31, ty0 = threadIdx.x >> 5;
    const u16* Vin = QKV + 2048;                  // V cols of QKV (ld 3072)
#pragma unroll
    for (int k = 0; k < 4; ++k) {
      const int ty = ty0 + k * 8;
      tl[ty][tx] = Vin[(size_t)(r0 + ty) * 3072 + c0 + tx];
    }
    __syncthreads();
#pragma unroll
    for (int k = 0; k < 4; ++k) {
      const int ty = ty0 + k * 8;
      Vt[(size_t)(c0 + ty) * 4096 + r0 + tx] = tl[tx][ty];
    }
  }
}

// -------------------------------------------------------------------------
// S=4096, D_IN=1024, D_OUT=1024.  fp32 in, fp32 out.
// ws (bytes): Ebf 0-8M | Wt 8-14M | QKV 14-38M | Vt 38-46M | S 46-78M.
// PV partials: f32 64MB @78M if ws >= 146MB, else bf16 32MB @0.
// 6 dispatches: prep -> qkv -> score -> softmax+tV -> pv-splitK -> reduce.
// All GEMMs: 128x256 tile, BK=32, 3-buf ring, 1 barrier/K-tile, 2 blk/CU.
// -------------------------------------------------------------------------
extern "C" void kernel_launch(void* const* d_in, const int* in_sizes, int n_in,
                              void* d_out, int out_size, void* d_ws, size_t ws_size,
                              hipStream_t stream) {
  const float* E  = (const float*)d_in[0];
  const float* Wq = (const float*)d_in[1];
  const float* Wk = (const float*)d_in[2];
  const float* Wv = (const float*)d_in[3];
  float* Out = (float*)d_out;

  char* w = (char*)d_ws;
  u16* Ebf = (u16*)(w);
  u16* Wt  = (u16*)(w + (size_t)(8u << 20));
  u16* QKV = (u16*)(w + (size_t)(14u << 20));
  u16* Vt  = (u16*)(w + (size_t)(38u << 20));
  u16* S   = (u16*)(w + (size_t)(46u << 20));

  // stage 0: E cast + W transposes
  prep<<<7168, 256, 0, stream>>>(E, Wq, Wk, Wv, Ebf, Wt);

  // stage 1: QKV = E @ Wt^T   [4096 x 3072], K=1024
  gemm_qkv128<<<384, 512, 0, stream>>>(Ebf, Wt, QKV);

  // stage 2: S = (Q @ K^T) / 32
  gemm_score128<<<512, 512, 0, stream>>>(QKV, S);

  // stage 3: P = softmax(S) in place  +  V^T
  softmax_tv<<<8192, 256, 0, stream>>>(S, QKV, Vt);

  // stage 4+5: Out = P @ Vt^T via split-K x4 + reduce
  if (ws_size >= ((size_t)146u << 20)) {
    float* P4 = (float*)(w + ((size_t)78u << 20));
    gemm_pv128f<<<512, 512, 0, stream>>>(S, Vt, P4);
    reduce4f<<<4096, 256, 0, stream>>>(P4, Out);
  } else {
    u16* P4 = (u16*)w;                    // aliases dead Ebf/Wt/QKV
    gemm_pv128h<<<512, 512, 0, stream>>>(S, Vt, P4);
    reduce4h<<<4096, 256, 0, stream>>>(P4, Out);
  }
}